// Round 5
// baseline (447.767 us; speedup 1.0000x reference)
//
#include <hip/hip_runtime.h>
#include <hip/hip_bf16.h>
#include <cstdio>

// Problem constants (B=2, T=2048, D=1024, H=4096, O=1024, E=8, top-k=2)
#define NT_TOK 4096
#define D_DIM  1024
#define H_DIM  4096
#define O_DIM  1024
#define E_NUM  8
#define PAIRS  8192      // NT_TOK * 2
#define WI_SLOTS 40      // max m-tiles at BM=256: 32 + 7 rounding < 40
#define BK 64

typedef short bf16x8 __attribute__((ext_vector_type(8)));
typedef float f32x4  __attribute__((ext_vector_type(4)));

// round-to-nearest-even fp32 -> bf16 bits
__device__ __forceinline__ unsigned short bfr(float f){
  unsigned u = __float_as_uint(f);
  unsigned r = (u + 0x7FFFu + ((u >> 16) & 1u)) >> 16;
  return (unsigned short)r;
}

// async global->LDS, 16B per lane; lds dest is wave-uniform base (HW adds lane*16)
__device__ __forceinline__ void gload_lds16(const void* g, void* l){
  __builtin_amdgcn_global_load_lds((const __attribute__((address_space(1))) unsigned int*)g,
                                   (__attribute__((address_space(3))) unsigned int*)l,
                                   16, 0, 0);
}

// ---------------------------------------------------------------- cast x -> bf16
__global__ __launch_bounds__(256) void cast_x_kernel(const float* __restrict__ x,
                                                     unsigned short* __restrict__ xb){
  int i = blockIdx.x * 256 + threadIdx.x;           // over float4s: NT*D/4 = 1M
  const float4 v = ((const float4*)x)[i];
  unsigned short r0 = bfr(v.x), r1 = bfr(v.y), r2 = bfr(v.z), r3 = bfr(v.w);
  unsigned int p0 = (unsigned int)r0 | ((unsigned int)r1 << 16);
  unsigned int p1 = (unsigned int)r2 | ((unsigned int)r3 << 16);
  ((uint2*)xb)[i] = make_uint2(p0, p1);
}

// ------------------------- cast+transpose [R][C] f32 -> [C][R] bf16, 64x64 tiles
__global__ __launch_bounds__(256) void transpose_cast64(const float* __restrict__ in,
                                                        unsigned short* __restrict__ out,
                                                        int R, int C){
  __shared__ float t[64][65];
  long long base = (long long)blockIdx.z * R * C;
  int c0 = blockIdx.x * 64, r0 = blockIdx.y * 64;
  int tid = threadIdx.x;
  int rr = tid >> 4;           // 0..15
  int cc = (tid & 15) * 4;     // 0,4,...,60
  #pragma unroll
  for (int i = 0; i < 4; i++){
    int r = rr + i * 16;
    float4 v = *(const float4*)&in[base + (long long)(r0 + r) * C + c0 + cc];
    t[r][cc] = v.x; t[r][cc+1] = v.y; t[r][cc+2] = v.z; t[r][cc+3] = v.w;
  }
  __syncthreads();
  #pragma unroll
  for (int i = 0; i < 4; i++){
    int oc = rr + i * 16;      // output row (= input col)
    unsigned int lo = (unsigned int)bfr(t[cc][oc])   | ((unsigned int)bfr(t[cc+1][oc]) << 16);
    unsigned int hi = (unsigned int)bfr(t[cc+2][oc]) | ((unsigned int)bfr(t[cc+3][oc]) << 16);
    *(uint2*)&out[base + (long long)(c0 + oc) * R + r0 + cc] = make_uint2(lo, hi);
  }
}

// ---------------------------------------------------------------- gating (top-2)
__global__ __launch_bounds__(256) void gating_kernel(const float* __restrict__ x,
                                                     const float* __restrict__ Wg,
                                                     const float* __restrict__ bg,
                                                     int*   __restrict__ pe,
                                                     float* __restrict__ pw){
  int wid = threadIdx.x >> 6, lane = threadIdx.x & 63;
  int t = blockIdx.x * 4 + wid;
  const float* xr = x + (long long)t * D_DIM;
  float acc[E_NUM];
  #pragma unroll
  for (int e = 0; e < E_NUM; e++) acc[e] = 0.f;
  for (int d = lane; d < D_DIM; d += 64){
    float xv = xr[d];
    const float* wr = Wg + d * E_NUM;
    #pragma unroll
    for (int e = 0; e < E_NUM; e++) acc[e] += xv * wr[e];
  }
  #pragma unroll
  for (int off = 32; off; off >>= 1)
    #pragma unroll
    for (int e = 0; e < E_NUM; e++) acc[e] += __shfl_xor(acc[e], off);
  if (lane == 0){
    float l[E_NUM];
    float m = -1e30f;
    #pragma unroll
    for (int e = 0; e < E_NUM; e++){ l[e] = acc[e] + bg[e]; m = fmaxf(m, l[e]); }
    float ex[E_NUM];
    #pragma unroll
    for (int e = 0; e < E_NUM; e++) ex[e] = expf(l[e] - m);
    int e0 = 0;
    #pragma unroll
    for (int e = 1; e < E_NUM; e++) if (ex[e] > ex[e0]) e0 = e;      // first max
    int e1 = -1;
    for (int e = 0; e < E_NUM; e++){ if (e == e0) continue; if (e1 < 0 || ex[e] > ex[e1]) e1 = e; }
    float s = ex[e0] + ex[e1];
    pe[2*t]   = e0;  pw[2*t]   = ex[e0] / s;
    pe[2*t+1] = e1;  pw[2*t+1] = ex[e1] / s;
  }
}

// ---------------------------------------------------------------- chunk histograms
__global__ __launch_bounds__(256) void hist_kernel(const int* __restrict__ pe,
                                                   int* __restrict__ chunk_hist){
  __shared__ int h[E_NUM];
  if (threadIdx.x < E_NUM) h[threadIdx.x] = 0;
  __syncthreads();
  int p = blockIdx.x * 256 + threadIdx.x;
  atomicAdd(&h[pe[p]], 1);
  __syncthreads();
  if (threadIdx.x < E_NUM) chunk_hist[blockIdx.x * E_NUM + threadIdx.x] = h[threadIdx.x];
}

// --------------------------------- scan + deterministic scatter + work-item table
__global__ __launch_bounds__(256) void scatter_kernel(const int* __restrict__ pe,
                                                      const int* __restrict__ chunk_hist,
                                                      int* __restrict__ cnt,
                                                      int* __restrict__ offs,
                                                      int* __restrict__ row_pair,
                                                      int* __restrict__ wi){
  __shared__ int hist[32][E_NUM];
  __shared__ int pref[32][E_NUM];
  __shared__ int total[E_NUM];
  __shared__ int off_s[E_NUM + 1];
  __shared__ unsigned char ex[PAIRS];
  int tid = threadIdx.x;
  for (int i = tid; i < PAIRS; i += 256) ex[i] = (unsigned char)pe[i];
  { int c = tid >> 3, e = tid & 7; hist[c][e] = chunk_hist[tid]; }
  __syncthreads();
  if (tid < E_NUM){
    int s = 0;
    for (int c = 0; c < 32; c++){ pref[c][tid] = s; s += hist[c][tid]; }
    total[tid] = s;
  }
  __syncthreads();
  if (tid == 0){
    int s = 0;
    for (int e = 0; e < E_NUM; e++){ off_s[e] = s; s += total[e]; }
    off_s[E_NUM] = s;
    // work-item table: (e<<8)|mt for every valid 256-row m-tile, -1 padding
    int idx = 0;
    for (int e = 0; e < E_NUM; e++){
      int mts = (total[e] + 255) >> 8;
      for (int m = 0; m < mts; m++) wi[idx++] = (e << 8) | m;
    }
    for (; idx < WI_SLOTS; idx++) wi[idx] = -1;
  }
  __syncthreads();
  if (tid < E_NUM){ cnt[tid] = total[tid]; offs[tid] = off_s[tid]; }
  int c = tid >> 3, e = tid & 7;
  int base = off_s[e] + pref[c][e];
  int local = 0;
  for (int i = 0; i < 256; i++){
    int p = c * 256 + i;
    if (ex[p] == (unsigned char)e){
      row_pair[base + local] = p;
      local++;
    }
  }
}

// ============================================================== grouped GEMM1
// 256x256 tile, BK=64, 512 thr (8 waves 2x4). T3-minimum 2-phase:
// STAGE(next) -> ds_read cur (2 sub-phases) -> lgkmcnt(0) -> MFMA -> vmcnt(0) -> barrier.
// One barrier + one vmcnt per K-tile.
#define CH1  80    // (16 nt * 40 slots) / 8 XCDs
__global__ __launch_bounds__(512, 2) void gemm1_kernel(const unsigned short* __restrict__ xb,
                                                       const unsigned short* __restrict__ W1t,
                                                       const float* __restrict__ b1,
                                                       const int* __restrict__ row_pair,
                                                       const int* __restrict__ cnt,
                                                       const int* __restrict__ offs,
                                                       const int* __restrict__ wi,
                                                       unsigned short* __restrict__ hidden){
  int f  = blockIdx.y * 16 + blockIdx.x;
  int fp = (f & 7) * CH1 + (f >> 3);      // bijective: 640 % 8 == 0
  int nt   = fp & 15;
  int slot = fp >> 4;
  int w = wi[slot];
  if (w < 0) return;
  int e = w >> 8, mt = w & 255;
  int count = cnt[e];
  int m0 = mt * 256;
  int seg = offs[e];
  int valid = count - m0;
  int n0 = nt * 256;

  __shared__ unsigned short As[2][256 * BK];
  __shared__ unsigned short Bs[2][256 * BK];

  int tid = threadIdx.x;
  int wv = tid >> 6, lane = tid & 63;
  int wr = wv >> 2, wc = wv & 3;          // wave rows wr*128..+127, cols wc*64..+63
  int lo = lane & 15, hi = lane >> 4;
  int l3 = lane >> 3;
  int srcel = ((lane & 7) ^ l3) << 3;     // inverse-swizzled source column (elements)

  const unsigned short* w1e = W1t + (long long)e * H_DIM * D_DIM;   // [H][D]

  const unsigned short* pa[2][2];
  const unsigned short* pb[2][2];
  #pragma unroll
  for (int h = 0; h < 2; h++)
    #pragma unroll
    for (int g = 0; g < 2; g++){
      int rloc = h * 128 + wv * 16 + g * 8 + l3;
      int pos = seg + m0 + rloc; if (pos > PAIRS - 1) pos = PAIRS - 1;
      int token = row_pair[pos] >> 1;
      pa[h][g] = xb + (long long)token * D_DIM + srcel;
      pb[h][g] = w1e + (long long)(n0 + rloc) * D_DIM + srcel;
    }

  auto STAGE = [&](int b){
    #pragma unroll
    for (int h = 0; h < 2; h++)
      #pragma unroll
      for (int g = 0; g < 2; g++){
        gload_lds16(pb[h][g], &Bs[b][(h*128 + wv*16 + g*8) * BK]);  pb[h][g] += BK;
        gload_lds16(pa[h][g], &As[b][(h*128 + wv*16 + g*8) * BK]);  pa[h][g] += BK;
      }
  };

  f32x4 acc[8][4] = {};
  bf16x8 bq[4][2];
  auto RD_B = [&](int b){
    #pragma unroll
    for (int n = 0; n < 4; n++)
      #pragma unroll
      for (int ks = 0; ks < 2; ks++){
        int br = wc*64 + n*16 + lo;
        bq[n][ks] = *(const bf16x8*)&Bs[b][br*BK + ((ks*32 + hi*8) ^ ((br & 7) << 3))];
      }
  };
  auto RD_A = [&](int b, int half, bf16x8 (&aq)[4][2]){
    #pragma unroll
    for (int i = 0; i < 4; i++)
      #pragma unroll
      for (int ks = 0; ks < 2; ks++){
        int ar = wr*128 + (half*4 + i)*16 + lo;
        aq[i][ks] = *(const bf16x8*)&As[b][ar*BK + ((ks*32 + hi*8) ^ ((ar & 7) << 3))];
      }
  };
  auto MM = [&](int half, bf16x8 (&aq)[4][2]){
    __builtin_amdgcn_s_setprio(1);
    #pragma unroll
    for (int i = 0; i < 4; i++)
      #pragma unroll
      for (int n = 0; n < 4; n++)
        #pragma unroll
        for (int ks = 0; ks < 2; ks++)
          acc[half*4+i][n] = __builtin_amdgcn_mfma_f32_16x16x32_bf16(aq[i][ks], bq[n][ks], acc[half*4+i][n], 0, 0, 0);
    __builtin_amdgcn_s_setprio(0);
  };

  const int KT = D_DIM / BK;                 // 16
  STAGE(0);
  asm volatile("s_waitcnt vmcnt(0)" ::: "memory");
  __builtin_amdgcn_s_barrier();
  int cur = 0;
  for (int kt = 0; kt < KT - 1; ++kt){
    STAGE(cur ^ 1);                          // next tile's 8 loads, in flight under compute
    bf16x8 aq0[4][2], aq1[4][2];
    RD_B(cur); RD_A(cur, 0, aq0);
    asm volatile("s_waitcnt lgkmcnt(0)" ::: "memory");
    __builtin_amdgcn_sched_barrier(0);
    MM(0, aq0);
    RD_A(cur, 1, aq1);
    asm volatile("s_waitcnt lgkmcnt(0)" ::: "memory");
    __builtin_amdgcn_sched_barrier(0);
    MM(1, aq1);
    asm volatile("s_waitcnt vmcnt(0)" ::: "memory");
    __builtin_amdgcn_s_barrier();
    cur ^= 1;
  }
  {
    bf16x8 aq0[4][2], aq1[4][2];
    RD_B(cur); RD_A(cur, 0, aq0);
    asm volatile("s_waitcnt lgkmcnt(0)" ::: "memory");
    __builtin_amdgcn_sched_barrier(0);
    MM(0, aq0);
    RD_A(cur, 1, aq1);
    asm volatile("s_waitcnt lgkmcnt(0)" ::: "memory");
    __builtin_amdgcn_sched_barrier(0);
    MM(1, aq1);
  }

  const float* b1e = b1 + (long long)e * H_DIM;
  #pragma unroll
  for (int n = 0; n < 4; n++){
    int col = n0 + wc*64 + n*16 + lo;
    float bias = b1e[col];
    #pragma unroll
    for (int m = 0; m < 8; m++)
      #pragma unroll
      for (int j = 0; j < 4; j++){
        int rl = wr*128 + m*16 + hi*4 + j;
        if (rl < valid){
          float v = acc[m][n][j] + bias;
          v = v > 0.f ? v : 0.f;
          hidden[(long long)(seg + m0 + rl) * H_DIM + col] = bfr(v);
        }
      }
  }
}

// ============================================================== grouped GEMM2
// same 2-phase structure; split-K x nparts (blockIdx.z). KP = H_DIM/nparts.
__global__ __launch_bounds__(512, 2) void gemm2_kernel(const unsigned short* __restrict__ hidden,
                                                       const unsigned short* __restrict__ W2t,
                                                       const int* __restrict__ row_pair,
                                                       const int* __restrict__ cnt,
                                                       const int* __restrict__ offs,
                                                       const int* __restrict__ wi,
                                                       float* __restrict__ yA,
                                                       float* __restrict__ yB,
                                                       int KP){
  int nparts = gridDim.z;
  int ch = (4 * WI_SLOTS * nparts) >> 3;
  int f  = (blockIdx.z * WI_SLOTS + blockIdx.y) * 4 + blockIdx.x;
  int fp = (f & 7) * ch + (f >> 3);       // bijective: blocks % 8 == 0
  int nt    = fp & 3;
  int r2    = fp >> 2;
  int kpart = r2 / WI_SLOTS;
  int slot  = r2 % WI_SLOTS;
  int w = wi[slot];
  if (w < 0) return;
  int e = w >> 8, mt = w & 255;
  int count = cnt[e];
  int m0 = mt * 256;
  int seg = offs[e];
  int valid = count - m0;
  int n0 = nt * 256;
  int k0 = kpart * KP;
  float* y = (kpart < 2 ? yA : yB) + (long long)(kpart & 1) * PAIRS * O_DIM;

  __shared__ unsigned short As[2][256 * BK];
  __shared__ unsigned short Bs[2][256 * BK];

  int tid = threadIdx.x;
  int wv = tid >> 6, lane = tid & 63;
  int wr = wv >> 2, wc = wv & 3;
  int lo = lane & 15, hi = lane >> 4;
  int l3 = lane >> 3;
  int srcel = ((lane & 7) ^ l3) << 3;

  const unsigned short* w2e = W2t + (long long)e * O_DIM * H_DIM;   // [O][H]

  const unsigned short* pa[2][2];
  const unsigned short* pb[2][2];
  #pragma unroll
  for (int h = 0; h < 2; h++)
    #pragma unroll
    for (int g = 0; g < 2; g++){
      int rloc = h * 128 + wv * 16 + g * 8 + l3;
      long long pos = seg + m0 + rloc; if (pos > PAIRS - 1) pos = PAIRS - 1;
      pa[h][g] = hidden + pos * H_DIM + k0 + srcel;
      pb[h][g] = w2e + (long long)(n0 + rloc) * H_DIM + k0 + srcel;
    }

  auto STAGE = [&](int b){
    #pragma unroll
    for (int h = 0; h < 2; h++)
      #pragma unroll
      for (int g = 0; g < 2; g++){
        gload_lds16(pb[h][g], &Bs[b][(h*128 + wv*16 + g*8) * BK]);  pb[h][g] += BK;
        gload_lds16(pa[h][g], &As[b][(h*128 + wv*16 + g*8) * BK]);  pa[h][g] += BK;
      }
  };

  f32x4 acc[8][4] = {};
  bf16x8 bq[4][2];
  auto RD_B = [&](int b){
    #pragma unroll
    for (int n = 0; n < 4; n++)
      #pragma unroll
      for (int ks = 0; ks < 2; ks++){
        int br = wc*64 + n*16 + lo;
        bq[n][ks] = *(const bf16x8*)&Bs[b][br*BK + ((ks*32 + hi*8) ^ ((br & 7) << 3))];
      }
  };
  auto RD_A = [&](int b, int half, bf16x8 (&aq)[4][2]){
    #pragma unroll
    for (int i = 0; i < 4; i++)
      #pragma unroll
      for (int ks = 0; ks < 2; ks++){
        int ar = wr*128 + (half*4 + i)*16 + lo;
        aq[i][ks] = *(const bf16x8*)&As[b][ar*BK + ((ks*32 + hi*8) ^ ((ar & 7) << 3))];
      }
  };
  auto MM = [&](int half, bf16x8 (&aq)[4][2]){
    __builtin_amdgcn_s_setprio(1);
    #pragma unroll
    for (int i = 0; i < 4; i++)
      #pragma unroll
      for (int n = 0; n < 4; n++)
        #pragma unroll
        for (int ks = 0; ks < 2; ks++)
          acc[half*4+i][n] = __builtin_amdgcn_mfma_f32_16x16x32_bf16(aq[i][ks], bq[n][ks], acc[half*4+i][n], 0, 0, 0);
    __builtin_amdgcn_s_setprio(0);
  };

  const int KT = KP / BK;                    // 16 (nparts=4) or 32 (nparts=2)
  STAGE(0);
  asm volatile("s_waitcnt vmcnt(0)" ::: "memory");
  __builtin_amdgcn_s_barrier();
  int cur = 0;
  for (int kt = 0; kt < KT - 1; ++kt){
    STAGE(cur ^ 1);
    bf16x8 aq0[4][2], aq1[4][2];
    RD_B(cur); RD_A(cur, 0, aq0);
    asm volatile("s_waitcnt lgkmcnt(0)" ::: "memory");
    __builtin_amdgcn_sched_barrier(0);
    MM(0, aq0);
    RD_A(cur, 1, aq1);
    asm volatile("s_waitcnt lgkmcnt(0)" ::: "memory");
    __builtin_amdgcn_sched_barrier(0);
    MM(1, aq1);
    asm volatile("s_waitcnt vmcnt(0)" ::: "memory");
    __builtin_amdgcn_s_barrier();
    cur ^= 1;
  }
  {
    bf16x8 aq0[4][2], aq1[4][2];
    RD_B(cur); RD_A(cur, 0, aq0);
    asm volatile("s_waitcnt lgkmcnt(0)" ::: "memory");
    __builtin_amdgcn_sched_barrier(0);
    MM(0, aq0);
    RD_A(cur, 1, aq1);
    asm volatile("s_waitcnt lgkmcnt(0)" ::: "memory");
    __builtin_amdgcn_sched_barrier(0);
    MM(1, aq1);
  }

  #pragma unroll
  for (int m = 0; m < 8; m++)
    #pragma unroll
    for (int j = 0; j < 4; j++){
      int rl = wr*128 + m*16 + hi*4 + j;
      if (rl < valid){
        int p = row_pair[seg + m0 + rl];
        float* yr = y + (long long)p * O_DIM;
        #pragma unroll
        for (int n = 0; n < 4; n++){
          int col = n0 + wc*64 + n*16 + lo;
          yr[col] = acc[m][n][j];
        }
      }
    }
}

// ---------------------------------------------------------------- combine
__global__ __launch_bounds__(256) void combine_kernel(const float* __restrict__ yA,
                                                      const float* __restrict__ yB,
                                                      int nparts,
                                                      const float* __restrict__ b2,
                                                      const int* __restrict__ pe,
                                                      const float* __restrict__ pw,
                                                      float* __restrict__ out){
  int t = blockIdx.x, tid = threadIdx.x;      // 256 threads * float4 = 1024 = O_DIM
  int e0 = pe[2*t], e1 = pe[2*t+1];
  float w0 = pw[2*t], w1 = pw[2*t+1];
  float4 s0 = make_float4(0.f,0.f,0.f,0.f), s1 = make_float4(0.f,0.f,0.f,0.f);
  for (int p = 0; p < nparts; p++){
    const float* yp = (p < 2 ? yA : yB) + (long long)(p & 1) * PAIRS * O_DIM;
    float4 a = ((const float4*)(yp + (long long)(2*t) * O_DIM))[tid];
    float4 b = ((const float4*)(yp + (long long)(2*t+1) * O_DIM))[tid];
    s0.x += a.x; s0.y += a.y; s0.z += a.z; s0.w += a.w;
    s1.x += b.x; s1.y += b.y; s1.z += b.z; s1.w += b.w;
  }
  float4 ca = ((const float4*)(b2 + (long long)e0 * O_DIM))[tid];
  float4 cb = ((const float4*)(b2 + (long long)e1 * O_DIM))[tid];
  float4 r;
  r.x = w0 * (s0.x + ca.x) + w1 * (s1.x + cb.x);
  r.y = w0 * (s0.y + ca.y) + w1 * (s1.y + cb.y);
  r.z = w0 * (s0.z + ca.z) + w1 * (s1.z + cb.z);
  r.w = w0 * (s0.w + ca.w) + w1 * (s1.w + cb.w);
  ((float4*)(out + (long long)t * O_DIM))[tid] = r;
}

// ---------------------------------------------------------------- host
extern "C" void kernel_launch(void* const* d_in, const int* in_sizes, int n_in,
                              void* d_out, int out_size, void* d_ws, size_t ws_size,
                              hipStream_t stream){
  const float* x  = (const float*)d_in[0];
  const float* Wg = (const float*)d_in[1];
  const float* bg = (const float*)d_in[2];
  const float* W1 = (const float*)d_in[3];
  const float* b1 = (const float*)d_in[4];
  const float* W2 = (const float*)d_in[5];
  const float* b2 = (const float*)d_in[6];
  float* out = (float*)d_out;

  char* ws = (char*)d_ws;
  size_t off = 0;
  auto alloc = [&](size_t bytes){ size_t r = off; off += (bytes + 255) & ~(size_t)255; return r; };

  unsigned short* W1t    = (unsigned short*)(ws + alloc((size_t)E_NUM * H_DIM * D_DIM * 2));
  unsigned short* W2t    = (unsigned short*)(ws + alloc((size_t)E_NUM * O_DIM * H_DIM * 2));
  unsigned short* xb     = (unsigned short*)(ws + alloc((size_t)NT_TOK * D_DIM * 2));
  unsigned short* hidden = (unsigned short*)(ws + alloc((size_t)PAIRS * H_DIM * 2));
  int*            pe     = (int*)           (ws + alloc(PAIRS * 4));
  float*          pw     = (float*)         (ws + alloc(PAIRS * 4));
  int*            row_pair = (int*)         (ws + alloc(PAIRS * 4));
  int*            cnt    = (int*)           (ws + alloc(64));
  int*            offs   = (int*)           (ws + alloc(64));
  int*            chist  = (int*)           (ws + alloc(32 * E_NUM * 4));
  int*            wi     = (int*)           (ws + alloc(WI_SLOTS * 4));
  size_t base_need = off;

  // y partials: parts 0,1 alias W1t (dead after gemm1). Parts 2,3 need fresh 64 MiB.
  float* yA = (float*)W1t;
  int nparts = 2;
  float* yB = nullptr;
  size_t extra = (size_t)2 * PAIRS * O_DIM * 4;
  if (base_need + extra <= ws_size){
    yB = (float*)(ws + alloc(extra));
    nparts = 4;
  }
  if (base_need > ws_size)
    fprintf(stderr, "kernel_launch: workspace too small: need %zu, have %zu\n", base_need, ws_size);

  cast_x_kernel<<<(NT_TOK * D_DIM / 4) / 256, 256, 0, stream>>>(x, xb);
  transpose_cast64<<<dim3(H_DIM/64, D_DIM/64, E_NUM), 256, 0, stream>>>(W1, W1t, D_DIM, H_DIM);
  transpose_cast64<<<dim3(O_DIM/64, H_DIM/64, E_NUM), 256, 0, stream>>>(W2, W2t, H_DIM, O_DIM);
  gating_kernel<<<NT_TOK/4, 256, 0, stream>>>(x, Wg, bg, pe, pw);
  hist_kernel<<<PAIRS/256, 256, 0, stream>>>(pe, chist);
  scatter_kernel<<<1, 256, 0, stream>>>(pe, chist, cnt, offs, row_pair, wi);
  gemm1_kernel<<<dim3(H_DIM/256, WI_SLOTS), 512, 0, stream>>>(xb, W1t, b1, row_pair, cnt, offs, wi, hidden);
  gemm2_kernel<<<dim3(O_DIM/256, WI_SLOTS, nparts), 512, 0, stream>>>(hidden, W2t, row_pair, cnt, offs, wi,
                                                                     yA, yB ? yB : yA, H_DIM / nparts);
  combine_kernel<<<NT_TOK, 256, 0, stream>>>(yA, yB ? yB : yA, nparts, b2, pe, pw, out);
}

// Round 6
// 339.084 us; speedup vs baseline: 1.3205x; 1.3205x over previous
//
#include <hip/hip_runtime.h>
#include <hip/hip_bf16.h>
#include <cstdio>

// Problem constants (B=2, T=2048, D=1024, H=4096, O=1024, E=8, top-k=2)
#define NT_TOK 4096
#define D_DIM  1024
#define H_DIM  4096
#define O_DIM  1024
#define E_NUM  8
#define PAIRS  8192      // NT_TOK * 2
#define WI_SLOTS 72      // max m-tiles at BM=128: 64 + 7 rounding < 72
#define BK 64

typedef short bf16x8 __attribute__((ext_vector_type(8)));
typedef float f32x4  __attribute__((ext_vector_type(4)));

// round-to-nearest-even fp32 -> bf16 bits
__device__ __forceinline__ unsigned short bfr(float f){
  unsigned u = __float_as_uint(f);
  unsigned r = (u + 0x7FFFu + ((u >> 16) & 1u)) >> 16;
  return (unsigned short)r;
}

// async global->LDS, 16B per lane; lds dest is wave-uniform base (HW adds lane*16)
__device__ __forceinline__ void gload_lds16(const void* g, void* l){
  __builtin_amdgcn_global_load_lds((const __attribute__((address_space(1))) unsigned int*)g,
                                   (__attribute__((address_space(3))) unsigned int*)l,
                                   16, 0, 0);
}

// ------------------------- cast+transpose [R][C] f32 -> [C][R] bf16, 64x64 tiles
__global__ __launch_bounds__(256) void transpose_cast64(const float* __restrict__ in,
                                                        unsigned short* __restrict__ out,
                                                        int R, int C){
  __shared__ float t[64][65];
  long long base = (long long)blockIdx.z * R * C;
  int c0 = blockIdx.x * 64, r0 = blockIdx.y * 64;
  int tid = threadIdx.x;
  int rr = tid >> 4;           // 0..15
  int cc = (tid & 15) * 4;     // 0,4,...,60
  #pragma unroll
  for (int i = 0; i < 4; i++){
    int r = rr + i * 16;
    float4 v = *(const float4*)&in[base + (long long)(r0 + r) * C + c0 + cc];
    t[r][cc] = v.x; t[r][cc+1] = v.y; t[r][cc+2] = v.z; t[r][cc+3] = v.w;
  }
  __syncthreads();
  #pragma unroll
  for (int i = 0; i < 4; i++){
    int oc = rr + i * 16;      // output row (= input col)
    unsigned int lo = (unsigned int)bfr(t[cc][oc])   | ((unsigned int)bfr(t[cc+1][oc]) << 16);
    unsigned int hi = (unsigned int)bfr(t[cc+2][oc]) | ((unsigned int)bfr(t[cc+3][oc]) << 16);
    *(uint2*)&out[base + (long long)(c0 + oc) * R + r0 + cc] = make_uint2(lo, hi);
  }
}

// -------------------------------- gating (top-2) + fused x -> bf16 cast
__global__ __launch_bounds__(256) void gating_kernel(const float* __restrict__ x,
                                                     const float* __restrict__ Wg,
                                                     const float* __restrict__ bg,
                                                     unsigned short* __restrict__ xb,
                                                     int*   __restrict__ pe,
                                                     float* __restrict__ pw){
  int wid = threadIdx.x >> 6, lane = threadIdx.x & 63;
  int t = blockIdx.x * 4 + wid;
  const float* xr = x + (long long)t * D_DIM;
  unsigned short* xo = xb + (long long)t * D_DIM;
  float acc[E_NUM];
  #pragma unroll
  for (int e = 0; e < E_NUM; e++) acc[e] = 0.f;
  for (int d = lane; d < D_DIM; d += 64){
    float xv = xr[d];
    xo[d] = bfr(xv);                          // fused bf16 cast (coalesced 128B/wave)
    const float* wr = Wg + d * E_NUM;
    #pragma unroll
    for (int e = 0; e < E_NUM; e++) acc[e] += xv * wr[e];
  }
  #pragma unroll
  for (int off = 32; off; off >>= 1)
    #pragma unroll
    for (int e = 0; e < E_NUM; e++) acc[e] += __shfl_xor(acc[e], off);
  if (lane == 0){
    float l[E_NUM];
    float m = -1e30f;
    #pragma unroll
    for (int e = 0; e < E_NUM; e++){ l[e] = acc[e] + bg[e]; m = fmaxf(m, l[e]); }
    float ex[E_NUM];
    #pragma unroll
    for (int e = 0; e < E_NUM; e++) ex[e] = expf(l[e] - m);
    int e0 = 0;
    #pragma unroll
    for (int e = 1; e < E_NUM; e++) if (ex[e] > ex[e0]) e0 = e;      // first max
    int e1 = -1;
    for (int e = 0; e < E_NUM; e++){ if (e == e0) continue; if (e1 < 0 || ex[e] > ex[e1]) e1 = e; }
    float s = ex[e0] + ex[e1];
    pe[2*t]   = e0;  pw[2*t]   = ex[e0] / s;
    pe[2*t+1] = e1;  pw[2*t+1] = ex[e1] / s;
  }
}

// ---------------------------------------------------------------- chunk histograms
__global__ __launch_bounds__(256) void hist_kernel(const int* __restrict__ pe,
                                                   int* __restrict__ chunk_hist){
  __shared__ int h[E_NUM];
  if (threadIdx.x < E_NUM) h[threadIdx.x] = 0;
  __syncthreads();
  int p = blockIdx.x * 256 + threadIdx.x;
  atomicAdd(&h[pe[p]], 1);
  __syncthreads();
  if (threadIdx.x < E_NUM) chunk_hist[blockIdx.x * E_NUM + threadIdx.x] = h[threadIdx.x];
}

// --------------------------------- scan + deterministic scatter + work-item table
__global__ __launch_bounds__(256) void scatter_kernel(const int* __restrict__ pe,
                                                      const int* __restrict__ chunk_hist,
                                                      int* __restrict__ cnt,
                                                      int* __restrict__ offs,
                                                      int* __restrict__ row_pair,
                                                      int* __restrict__ wi){
  __shared__ int hist[32][E_NUM];
  __shared__ int pref[32][E_NUM];
  __shared__ int total[E_NUM];
  __shared__ int off_s[E_NUM + 1];
  __shared__ unsigned char ex[PAIRS];
  int tid = threadIdx.x;
  for (int i = tid; i < PAIRS; i += 256) ex[i] = (unsigned char)pe[i];
  { int c = tid >> 3, e = tid & 7; hist[c][e] = chunk_hist[tid]; }
  __syncthreads();
  if (tid < E_NUM){
    int s = 0;
    for (int c = 0; c < 32; c++){ pref[c][tid] = s; s += hist[c][tid]; }
    total[tid] = s;
  }
  __syncthreads();
  if (tid == 0){
    int s = 0;
    for (int e = 0; e < E_NUM; e++){ off_s[e] = s; s += total[e]; }
    off_s[E_NUM] = s;
    // work-item table: (e<<8)|mt for every valid 128-row m-tile, -1 padding
    int idx = 0;
    for (int e = 0; e < E_NUM; e++){
      int mts = (total[e] + 127) >> 7;
      for (int m = 0; m < mts; m++) wi[idx++] = (e << 8) | m;
    }
    for (; idx < WI_SLOTS; idx++) wi[idx] = -1;
  }
  __syncthreads();
  if (tid < E_NUM){ cnt[tid] = total[tid]; offs[tid] = off_s[tid]; }
  int c = tid >> 3, e = tid & 7;
  int base = off_s[e] + pref[c][e];
  int local = 0;
  for (int i = 0; i < 256; i++){
    int p = c * 256 + i;
    if (ex[p] == (unsigned char)e){
      row_pair[base + local] = p;
      local++;
    }
  }
}

// ============================================================== grouped GEMM1
// m97 structure: 128x128 tile, BK=64, 256 thr (4 waves 2x2), single-buffer 32KB LDS,
// STAGE -> sync -> COMPUTE -> sync. Co-residency (3 blocks/CU) hides latency.
// hidden[pos][h] = relu( x[token(pos)] . W1[e][:, h] + b1[e][h] ), bf16 out
__global__ __launch_bounds__(256, 3) void gemm1_kernel(const unsigned short* __restrict__ xb,
                                                       const unsigned short* __restrict__ W1t,
                                                       const float* __restrict__ b1,
                                                       const int* __restrict__ row_pair,
                                                       const int* __restrict__ cnt,
                                                       const int* __restrict__ offs,
                                                       const int* __restrict__ wi,
                                                       unsigned short* __restrict__ hidden){
  int w = wi[blockIdx.y];
  if (w < 0) return;
  int e = w >> 8, mt = w & 255;
  int nt = blockIdx.x;                        // 0..31
  int count = cnt[e];
  int m0 = mt * 128;
  int seg = offs[e];
  int valid = count - m0;
  int n0 = nt * 128;

  __shared__ unsigned short As[128 * BK];
  __shared__ unsigned short Bs[128 * BK];

  int tid = threadIdx.x;
  int wv = tid >> 6, lane = tid & 63;
  int wr = wv >> 1, wc = wv & 1;              // wave tile: rows wr*64..+63, cols wc*64..+63
  int lo = lane & 15, hi = lane >> 4;
  int l3 = lane >> 3;                         // 0..7 (= staged row & 7)
  int srcel = ((lane & 7) ^ l3) << 3;         // inverse-swizzled source column (elements)

  const unsigned short* w1e = W1t + (long long)e * H_DIM * D_DIM;   // [H][D]

  // staging: call h covers LDS rows h*32 + wv*8 + l3 (4 calls each for A and B)
  const unsigned short* pa[4];
  const unsigned short* pb[4];
  #pragma unroll
  for (int h = 0; h < 4; h++){
    int r = h * 32 + wv * 8 + l3;
    int pos = seg + m0 + r; if (pos > PAIRS - 1) pos = PAIRS - 1;
    int token = row_pair[pos] >> 1;
    pa[h] = xb + (long long)token * D_DIM + srcel;
    pb[h] = w1e + (long long)(n0 + r) * D_DIM + srcel;
  }

  f32x4 acc[4][4] = {};
  for (int kt = 0; kt < D_DIM / BK; ++kt){
    #pragma unroll
    for (int h = 0; h < 4; h++){
      gload_lds16(pa[h], &As[(h*32 + wv*8) * BK]);  pa[h] += BK;
      gload_lds16(pb[h], &Bs[(h*32 + wv*8) * BK]);  pb[h] += BK;
    }
    __syncthreads();
    bf16x8 aq[4][2], bq[4][2];
    #pragma unroll
    for (int n = 0; n < 4; n++)
      #pragma unroll
      for (int ks = 0; ks < 2; ks++){
        int br = wc*64 + n*16 + lo;
        bq[n][ks] = *(const bf16x8*)&Bs[br*BK + ((ks*32 + hi*8) ^ ((br & 7) << 3))];
      }
    #pragma unroll
    for (int m = 0; m < 4; m++)
      #pragma unroll
      for (int ks = 0; ks < 2; ks++){
        int ar = wr*64 + m*16 + lo;
        aq[m][ks] = *(const bf16x8*)&As[ar*BK + ((ks*32 + hi*8) ^ ((ar & 7) << 3))];
      }
    #pragma unroll
    for (int m = 0; m < 4; m++)
      #pragma unroll
      for (int n = 0; n < 4; n++)
        #pragma unroll
        for (int ks = 0; ks < 2; ks++)
          acc[m][n] = __builtin_amdgcn_mfma_f32_16x16x32_bf16(aq[m][ks], bq[n][ks], acc[m][n], 0, 0, 0);
    __syncthreads();
  }

  const float* b1e = b1 + (long long)e * H_DIM;
  #pragma unroll
  for (int n = 0; n < 4; n++){
    int col = n0 + wc*64 + n*16 + lo;
    float bias = b1e[col];
    #pragma unroll
    for (int m = 0; m < 4; m++)
      #pragma unroll
      for (int j = 0; j < 4; j++){
        int rl = wr*64 + m*16 + hi*4 + j;
        if (rl < valid){
          float v = acc[m][n][j] + bias;
          v = v > 0.f ? v : 0.f;
          hidden[(long long)(seg + m0 + rl) * H_DIM + col] = bfr(v);
        }
      }
  }
}

// ============================================================== grouped GEMM2
// same m97 structure; split-K x2 (blockIdx.z) for block-count & co-residency.
__global__ __launch_bounds__(256, 3) void gemm2_kernel(const unsigned short* __restrict__ hidden,
                                                       const unsigned short* __restrict__ W2t,
                                                       const int* __restrict__ row_pair,
                                                       const int* __restrict__ cnt,
                                                       const int* __restrict__ offs,
                                                       const int* __restrict__ wi,
                                                       float* __restrict__ yp){
  int w = wi[blockIdx.y];
  if (w < 0) return;
  int e = w >> 8, mt = w & 255;
  int nt = blockIdx.x;                        // 0..7
  int kpart = blockIdx.z;                     // 0..1
  int count = cnt[e];
  int m0 = mt * 128;
  int seg = offs[e];
  int valid = count - m0;
  int n0 = nt * 128;
  int k0 = kpart * (H_DIM / 2);
  float* y = yp + (long long)kpart * PAIRS * O_DIM;

  __shared__ unsigned short As[128 * BK];
  __shared__ unsigned short Bs[128 * BK];

  int tid = threadIdx.x;
  int wv = tid >> 6, lane = tid & 63;
  int wr = wv >> 1, wc = wv & 1;
  int lo = lane & 15, hi = lane >> 4;
  int l3 = lane >> 3;
  int srcel = ((lane & 7) ^ l3) << 3;

  const unsigned short* w2e = W2t + (long long)e * O_DIM * H_DIM;   // [O][H]

  const unsigned short* pa[4];
  const unsigned short* pb[4];
  #pragma unroll
  for (int h = 0; h < 4; h++){
    int r = h * 32 + wv * 8 + l3;
    long long pos = seg + m0 + r; if (pos > PAIRS - 1) pos = PAIRS - 1;
    pa[h] = hidden + pos * H_DIM + k0 + srcel;
    pb[h] = w2e + (long long)(n0 + r) * H_DIM + k0 + srcel;
  }

  f32x4 acc[4][4] = {};
  for (int kt = 0; kt < (H_DIM / 2) / BK; ++kt){
    #pragma unroll
    for (int h = 0; h < 4; h++){
      gload_lds16(pa[h], &As[(h*32 + wv*8) * BK]);  pa[h] += BK;
      gload_lds16(pb[h], &Bs[(h*32 + wv*8) * BK]);  pb[h] += BK;
    }
    __syncthreads();
    bf16x8 aq[4][2], bq[4][2];
    #pragma unroll
    for (int n = 0; n < 4; n++)
      #pragma unroll
      for (int ks = 0; ks < 2; ks++){
        int br = wc*64 + n*16 + lo;
        bq[n][ks] = *(const bf16x8*)&Bs[br*BK + ((ks*32 + hi*8) ^ ((br & 7) << 3))];
      }
    #pragma unroll
    for (int m = 0; m < 4; m++)
      #pragma unroll
      for (int ks = 0; ks < 2; ks++){
        int ar = wr*64 + m*16 + lo;
        aq[m][ks] = *(const bf16x8*)&As[ar*BK + ((ks*32 + hi*8) ^ ((ar & 7) << 3))];
      }
    #pragma unroll
    for (int m = 0; m < 4; m++)
      #pragma unroll
      for (int n = 0; n < 4; n++)
        #pragma unroll
        for (int ks = 0; ks < 2; ks++)
          acc[m][n] = __builtin_amdgcn_mfma_f32_16x16x32_bf16(aq[m][ks], bq[n][ks], acc[m][n], 0, 0, 0);
    __syncthreads();
  }

  #pragma unroll
  for (int m = 0; m < 4; m++)
    #pragma unroll
    for (int j = 0; j < 4; j++){
      int rl = wr*64 + m*16 + hi*4 + j;
      if (rl < valid){
        int p = row_pair[seg + m0 + rl];
        float* yr = y + (long long)p * O_DIM;
        #pragma unroll
        for (int n = 0; n < 4; n++){
          int col = n0 + wc*64 + n*16 + lo;
          yr[col] = acc[m][n][j];
        }
      }
    }
}

// ---------------------------------------------------------------- combine (2 k-parts)
__global__ __launch_bounds__(256) void combine_kernel(const float* __restrict__ yp,
                                                      const float* __restrict__ b2,
                                                      const int* __restrict__ pe,
                                                      const float* __restrict__ pw,
                                                      float* __restrict__ out){
  int t = blockIdx.x, tid = threadIdx.x;      // 256 threads * float4 = 1024 = O_DIM
  int e0 = pe[2*t], e1 = pe[2*t+1];
  float w0 = pw[2*t], w1 = pw[2*t+1];
  const float* y0 = yp;
  const float* y1 = yp + (long long)PAIRS * O_DIM;
  float4 a0 = ((const float4*)(y0 + (long long)(2*t) * O_DIM))[tid];
  float4 a1 = ((const float4*)(y1 + (long long)(2*t) * O_DIM))[tid];
  float4 b0 = ((const float4*)(y0 + (long long)(2*t+1) * O_DIM))[tid];
  float4 b1 = ((const float4*)(y1 + (long long)(2*t+1) * O_DIM))[tid];
  float4 ca = ((const float4*)(b2 + (long long)e0 * O_DIM))[tid];
  float4 cb = ((const float4*)(b2 + (long long)e1 * O_DIM))[tid];
  float4 r;
  r.x = w0 * (a0.x + a1.x + ca.x) + w1 * (b0.x + b1.x + cb.x);
  r.y = w0 * (a0.y + a1.y + ca.y) + w1 * (b0.y + b1.y + cb.y);
  r.z = w0 * (a0.z + a1.z + ca.z) + w1 * (b0.z + b1.z + cb.z);
  r.w = w0 * (a0.w + a1.w + ca.w) + w1 * (b0.w + b1.w + cb.w);
  ((float4*)(out + (long long)t * O_DIM))[tid] = r;
}

// ---------------------------------------------------------------- host
extern "C" void kernel_launch(void* const* d_in, const int* in_sizes, int n_in,
                              void* d_out, int out_size, void* d_ws, size_t ws_size,
                              hipStream_t stream){
  const float* x  = (const float*)d_in[0];
  const float* Wg = (const float*)d_in[1];
  const float* bg = (const float*)d_in[2];
  const float* W1 = (const float*)d_in[3];
  const float* b1 = (const float*)d_in[4];
  const float* W2 = (const float*)d_in[5];
  const float* b2 = (const float*)d_in[6];
  float* out = (float*)d_out;

  char* ws = (char*)d_ws;
  size_t off = 0;
  auto alloc = [&](size_t bytes){ size_t r = off; off += (bytes + 255) & ~(size_t)255; return r; };

  unsigned short* W1t    = (unsigned short*)(ws + alloc((size_t)E_NUM * H_DIM * D_DIM * 2));
  unsigned short* W2t    = (unsigned short*)(ws + alloc((size_t)E_NUM * O_DIM * H_DIM * 2));
  unsigned short* xb     = (unsigned short*)(ws + alloc((size_t)NT_TOK * D_DIM * 2));
  unsigned short* hidden = (unsigned short*)(ws + alloc((size_t)PAIRS * H_DIM * 2));
  int*            pe     = (int*)           (ws + alloc(PAIRS * 4));
  float*          pw     = (float*)         (ws + alloc(PAIRS * 4));
  int*            row_pair = (int*)         (ws + alloc(PAIRS * 4));
  int*            cnt    = (int*)           (ws + alloc(64));
  int*            offs   = (int*)           (ws + alloc(64));
  int*            chist  = (int*)           (ws + alloc(32 * E_NUM * 4));
  int*            wi     = (int*)           (ws + alloc(WI_SLOTS * 4));

  // y partials (2 x 32 MB) alias W1t (64 MB, dead after gemm1; stream order is safe)
  float* yp = (float*)W1t;

  if (off > ws_size)
    fprintf(stderr, "kernel_launch: workspace too small: need %zu, have %zu\n", off, ws_size);

  transpose_cast64<<<dim3(H_DIM/64, D_DIM/64, E_NUM), 256, 0, stream>>>(W1, W1t, D_DIM, H_DIM);
  transpose_cast64<<<dim3(O_DIM/64, H_DIM/64, E_NUM), 256, 0, stream>>>(W2, W2t, H_DIM, O_DIM);
  gating_kernel<<<NT_TOK/4, 256, 0, stream>>>(x, Wg, bg, xb, pe, pw);
  hist_kernel<<<PAIRS/256, 256, 0, stream>>>(pe, chist);
  scatter_kernel<<<1, 256, 0, stream>>>(pe, chist, cnt, offs, row_pair, wi);
  gemm1_kernel<<<dim3(H_DIM/128, WI_SLOTS), 256, 0, stream>>>(xb, W1t, b1, row_pair, cnt, offs, wi, hidden);
  gemm2_kernel<<<dim3(O_DIM/128, WI_SLOTS, 2), 256, 0, stream>>>(hidden, W2t, row_pair, cnt, offs, wi, yp);
  combine_kernel<<<NT_TOK, 256, 0, stream>>>(yp, b2, pe, pw, out);
}

// Round 7
// 324.009 us; speedup vs baseline: 1.3820x; 1.0465x over previous
//
#include <hip/hip_runtime.h>
#include <hip/hip_bf16.h>
#include <cstdio>

// Problem constants (B=2, T=2048, D=1024, H=4096, O=1024, E=8, top-k=2)
#define NT_TOK 4096
#define D_DIM  1024
#define H_DIM  4096
#define O_DIM  1024
#define E_NUM  8
#define PAIRS  8192      // NT_TOK * 2
#define WI_SLOTS 72      // max m-tiles at BM=128: 64 + 7 rounding < 72
#define BK 64
#define G1_BLOCKS (32 * WI_SLOTS)   // 2304 gemm1 blocks (nt 0..31, slot 0..71)
#define TW1_BLOCKS (E_NUM * 1024)   // 8192 W1-transpose tiles
#define TW2_BLOCKS (E_NUM * 1024)   // 8192 W2-transpose tiles

typedef short bf16x8 __attribute__((ext_vector_type(8)));
typedef float f32x4  __attribute__((ext_vector_type(4)));

// round-to-nearest-even fp32 -> bf16 bits
__device__ __forceinline__ unsigned short bfr(float f){
  unsigned u = __float_as_uint(f);
  unsigned r = (u + 0x7FFFu + ((u >> 16) & 1u)) >> 16;
  return (unsigned short)r;
}

// async global->LDS, 16B per lane; lds dest is wave-uniform base (HW adds lane*16)
__device__ __forceinline__ void gload_lds16(const void* g, void* l){
  __builtin_amdgcn_global_load_lds((const __attribute__((address_space(1))) unsigned int*)g,
                                   (__attribute__((address_space(3))) unsigned int*)l,
                                   16, 0, 0);
}

// ---------------- 64x64 cast+transpose tile body ([R][C] f32 -> [C][R] bf16)
__device__ __forceinline__ void transpose_tile(const float* __restrict__ in,
                                               unsigned short* __restrict__ out,
                                               int R, int C, int bx, int by, int bz,
                                               char* smem){
  float (*t)[65] = (float(*)[65])smem;
  long long base = (long long)bz * R * C;
  int c0 = bx * 64, r0 = by * 64;
  int tid = threadIdx.x;
  int rr = tid >> 4;           // 0..15
  int cc = (tid & 15) * 4;     // 0,4,...,60
  #pragma unroll
  for (int i = 0; i < 4; i++){
    int r = rr + i * 16;
    float4 v = *(const float4*)&in[base + (long long)(r0 + r) * C + c0 + cc];
    t[r][cc] = v.x; t[r][cc+1] = v.y; t[r][cc+2] = v.z; t[r][cc+3] = v.w;
  }
  __syncthreads();
  #pragma unroll
  for (int i = 0; i < 4; i++){
    int oc = rr + i * 16;      // output row (= input col)
    unsigned int lo = (unsigned int)bfr(t[cc][oc])   | ((unsigned int)bfr(t[cc+1][oc]) << 16);
    unsigned int hi = (unsigned int)bfr(t[cc+2][oc]) | ((unsigned int)bfr(t[cc+3][oc]) << 16);
    *(uint2*)&out[base + (long long)(c0 + oc) * R + r0 + cc] = make_uint2(lo, hi);
  }
}

// ================== K1: gating (top-2) + fused hist + x->bf16 cast  ∥  W1 transpose
__global__ __launch_bounds__(256) void gate_w1t_kernel(const float* __restrict__ x,
                                                       const float* __restrict__ Wg,
                                                       const float* __restrict__ bg,
                                                       const float* __restrict__ W1,
                                                       unsigned short* __restrict__ xb,
                                                       unsigned short* __restrict__ W1t,
                                                       int*   __restrict__ pe,
                                                       float* __restrict__ pw,
                                                       int*   __restrict__ chist){
  __shared__ __align__(16) char smem[16640];
  int bid = blockIdx.x;
  if (bid >= NT_TOK/4){
    // W1 [D][H] -> W1t [H][D] per expert; grid mapping: bx over H/64 (64), by over D/64 (16)
    int tb = bid - NT_TOK/4;
    int e = tb >> 10, t = tb & 1023;
    transpose_tile(W1, W1t, D_DIM, H_DIM, t & 63, t >> 6, e, smem);
    return;
  }
  int wid = threadIdx.x >> 6, lane = threadIdx.x & 63;
  int t = bid * 4 + wid;
  const float* xr = x + (long long)t * D_DIM;
  unsigned short* xo = xb + (long long)t * D_DIM;
  float acc[E_NUM];
  #pragma unroll
  for (int e = 0; e < E_NUM; e++) acc[e] = 0.f;
  for (int d = lane; d < D_DIM; d += 64){
    float xv = xr[d];
    xo[d] = bfr(xv);                          // fused bf16 cast
    const float* wr = Wg + d * E_NUM;
    #pragma unroll
    for (int e = 0; e < E_NUM; e++) acc[e] += xv * wr[e];
  }
  #pragma unroll
  for (int off = 32; off; off >>= 1)
    #pragma unroll
    for (int e = 0; e < E_NUM; e++) acc[e] += __shfl_xor(acc[e], off);
  if (lane == 0){
    float l[E_NUM];
    float m = -1e30f;
    #pragma unroll
    for (int e = 0; e < E_NUM; e++){ l[e] = acc[e] + bg[e]; m = fmaxf(m, l[e]); }
    float ex[E_NUM];
    #pragma unroll
    for (int e = 0; e < E_NUM; e++) ex[e] = expf(l[e] - m);
    int e0 = 0;
    #pragma unroll
    for (int e = 1; e < E_NUM; e++) if (ex[e] > ex[e0]) e0 = e;      // first max
    int e1 = -1;
    for (int e = 0; e < E_NUM; e++){ if (e == e0) continue; if (e1 < 0 || ex[e] > ex[e1]) e1 = e; }
    float s = ex[e0] + ex[e1];
    pe[2*t]   = e0;  pw[2*t]   = ex[e0] / s;
    pe[2*t+1] = e1;  pw[2*t+1] = ex[e1] / s;
    int chunk = (2*t) >> 8;                   // both pairs of t are in the same 256-chunk
    atomicAdd(&chist[chunk * E_NUM + e0], 1);
    atomicAdd(&chist[chunk * E_NUM + e1], 1);
  }
}

// --------------------------------- scan + deterministic scatter + work-item table
__global__ __launch_bounds__(256) void scatter_kernel(const int* __restrict__ pe,
                                                      const int* __restrict__ chunk_hist,
                                                      int* __restrict__ cnt,
                                                      int* __restrict__ offs,
                                                      int* __restrict__ row_pair,
                                                      int* __restrict__ wi){
  __shared__ int hist[32][E_NUM];
  __shared__ int pref[32][E_NUM];
  __shared__ int total[E_NUM];
  __shared__ int off_s[E_NUM + 1];
  __shared__ unsigned char ex[PAIRS];
  int tid = threadIdx.x;
  for (int i = tid; i < PAIRS; i += 256) ex[i] = (unsigned char)pe[i];
  { int c = tid >> 3, e = tid & 7; hist[c][e] = chunk_hist[tid]; }
  __syncthreads();
  if (tid < E_NUM){
    int s = 0;
    for (int c = 0; c < 32; c++){ pref[c][tid] = s; s += hist[c][tid]; }
    total[tid] = s;
  }
  __syncthreads();
  if (tid == 0){
    int s = 0;
    for (int e = 0; e < E_NUM; e++){ off_s[e] = s; s += total[e]; }
    off_s[E_NUM] = s;
    int idx = 0;
    for (int e = 0; e < E_NUM; e++){
      int mts = (total[e] + 127) >> 7;
      for (int m = 0; m < mts; m++) wi[idx++] = (e << 8) | m;
    }
    for (; idx < WI_SLOTS; idx++) wi[idx] = -1;
  }
  __syncthreads();
  if (tid < E_NUM){ cnt[tid] = total[tid]; offs[tid] = off_s[tid]; }
  int c = tid >> 3, e = tid & 7;
  int base = off_s[e] + pref[c][e];
  int local = 0;
  for (int i = 0; i < 256; i++){
    int p = c * 256 + i;
    if (ex[p] == (unsigned char)e){
      row_pair[base + local] = p;
      local++;
    }
  }
}

// ================== K4: grouped GEMM1 (m97 structure)  ∥  W2 transpose (tail-fill)
// hidden[pos][h] = relu( x[token(pos)] . W1[e][:, h] + b1[e][h] ), bf16 out
__global__ __launch_bounds__(256, 3) void gemm1_w2t_kernel(const unsigned short* __restrict__ xb,
                                                           const unsigned short* __restrict__ W1t,
                                                           const float* __restrict__ W2,
                                                           unsigned short* __restrict__ W2t,
                                                           const float* __restrict__ b1,
                                                           const int* __restrict__ row_pair,
                                                           const int* __restrict__ cnt,
                                                           const int* __restrict__ offs,
                                                           const int* __restrict__ wi,
                                                           unsigned short* __restrict__ hidden){
  __shared__ __align__(16) char smem[32768];
  int bid = blockIdx.x;
  if (bid >= G1_BLOCKS){
    // W2 [H][O] -> W2t [O][H] per expert; bx over O/64 (16), by over H/64 (64)
    int tb = bid - G1_BLOCKS;
    int e = tb >> 10, t = tb & 1023;
    transpose_tile(W2, W2t, H_DIM, O_DIM, t & 15, t >> 4, e, smem);
    return;
  }
  int nt = bid & 31, slot = bid >> 5;
  int w = wi[slot];
  if (w < 0) return;
  int e = w >> 8, mt = w & 255;
  int count = cnt[e];
  int m0 = mt * 128;
  int seg = offs[e];
  int valid = count - m0;
  int n0 = nt * 128;

  unsigned short* As = (unsigned short*)smem;            // 16 KB
  unsigned short* Bs = (unsigned short*)(smem + 16384);  // 16 KB

  int tid = threadIdx.x;
  int wv = tid >> 6, lane = tid & 63;
  int wr = wv >> 1, wc = wv & 1;              // wave tile: rows wr*64..+63, cols wc*64..+63
  int lo = lane & 15, hi = lane >> 4;
  int l3 = lane >> 3;                         // 0..7 (= staged row & 7)
  int srcel = ((lane & 7) ^ l3) << 3;         // inverse-swizzled source column (elements)

  const unsigned short* w1e = W1t + (long long)e * H_DIM * D_DIM;   // [H][D]

  const unsigned short* pa[4];
  const unsigned short* pb[4];
  #pragma unroll
  for (int h = 0; h < 4; h++){
    int r = h * 32 + wv * 8 + l3;
    int pos = seg + m0 + r; if (pos > PAIRS - 1) pos = PAIRS - 1;
    int token = row_pair[pos] >> 1;
    pa[h] = xb + (long long)token * D_DIM + srcel;
    pb[h] = w1e + (long long)(n0 + r) * D_DIM + srcel;
  }

  f32x4 acc[4][4] = {};
  for (int kt = 0; kt < D_DIM / BK; ++kt){
    #pragma unroll
    for (int h = 0; h < 4; h++){
      gload_lds16(pa[h], &As[(h*32 + wv*8) * BK]);  pa[h] += BK;
      gload_lds16(pb[h], &Bs[(h*32 + wv*8) * BK]);  pb[h] += BK;
    }
    __syncthreads();
    bf16x8 aq[4][2], bq[4][2];
    #pragma unroll
    for (int n = 0; n < 4; n++)
      #pragma unroll
      for (int ks = 0; ks < 2; ks++){
        int br = wc*64 + n*16 + lo;
        bq[n][ks] = *(const bf16x8*)&Bs[br*BK + ((ks*32 + hi*8) ^ ((br & 7) << 3))];
      }
    #pragma unroll
    for (int m = 0; m < 4; m++)
      #pragma unroll
      for (int ks = 0; ks < 2; ks++){
        int ar = wr*64 + m*16 + lo;
        aq[m][ks] = *(const bf16x8*)&As[ar*BK + ((ks*32 + hi*8) ^ ((ar & 7) << 3))];
      }
    #pragma unroll
    for (int m = 0; m < 4; m++)
      #pragma unroll
      for (int n = 0; n < 4; n++)
        #pragma unroll
        for (int ks = 0; ks < 2; ks++)
          acc[m][n] = __builtin_amdgcn_mfma_f32_16x16x32_bf16(aq[m][ks], bq[n][ks], acc[m][n], 0, 0, 0);
    __syncthreads();
  }

  const float* b1e = b1 + (long long)e * H_DIM;
  #pragma unroll
  for (int n = 0; n < 4; n++){
    int col = n0 + wc*64 + n*16 + lo;
    float bias = b1e[col];
    #pragma unroll
    for (int m = 0; m < 4; m++)
      #pragma unroll
      for (int j = 0; j < 4; j++){
        int rl = wr*64 + m*16 + hi*4 + j;
        if (rl < valid){
          float v = acc[m][n][j] + bias;
          v = v > 0.f ? v : 0.f;
          hidden[(long long)(seg + m0 + rl) * H_DIM + col] = bfr(v);
        }
      }
  }
}

// ============================================================== grouped GEMM2
// y[p][o] = hidden[pos] . W2[e][:,o] + b2[e][o]   (full K, no split)
__global__ __launch_bounds__(256, 3) void gemm2_kernel(const unsigned short* __restrict__ hidden,
                                                       const unsigned short* __restrict__ W2t,
                                                       const float* __restrict__ b2,
                                                       const int* __restrict__ row_pair,
                                                       const int* __restrict__ cnt,
                                                       const int* __restrict__ offs,
                                                       const int* __restrict__ wi,
                                                       float* __restrict__ y){
  int w = wi[blockIdx.y];
  if (w < 0) return;
  int e = w >> 8, mt = w & 255;
  int nt = blockIdx.x;                        // 0..7
  int count = cnt[e];
  int m0 = mt * 128;
  int seg = offs[e];
  int valid = count - m0;
  int n0 = nt * 128;

  __shared__ unsigned short As[128 * BK];
  __shared__ unsigned short Bs[128 * BK];

  int tid = threadIdx.x;
  int wv = tid >> 6, lane = tid & 63;
  int wr = wv >> 1, wc = wv & 1;
  int lo = lane & 15, hi = lane >> 4;
  int l3 = lane >> 3;
  int srcel = ((lane & 7) ^ l3) << 3;

  const unsigned short* w2e = W2t + (long long)e * O_DIM * H_DIM;   // [O][H]

  const unsigned short* pa[4];
  const unsigned short* pb[4];
  #pragma unroll
  for (int h = 0; h < 4; h++){
    int r = h * 32 + wv * 8 + l3;
    long long pos = seg + m0 + r; if (pos > PAIRS - 1) pos = PAIRS - 1;
    pa[h] = hidden + pos * H_DIM + srcel;
    pb[h] = w2e + (long long)(n0 + r) * H_DIM + srcel;
  }

  f32x4 acc[4][4] = {};
  for (int kt = 0; kt < H_DIM / BK; ++kt){
    #pragma unroll
    for (int h = 0; h < 4; h++){
      gload_lds16(pa[h], &As[(h*32 + wv*8) * BK]);  pa[h] += BK;
      gload_lds16(pb[h], &Bs[(h*32 + wv*8) * BK]);  pb[h] += BK;
    }
    __syncthreads();
    bf16x8 aq[4][2], bq[4][2];
    #pragma unroll
    for (int n = 0; n < 4; n++)
      #pragma unroll
      for (int ks = 0; ks < 2; ks++){
        int br = wc*64 + n*16 + lo;
        bq[n][ks] = *(const bf16x8*)&Bs[br*BK + ((ks*32 + hi*8) ^ ((br & 7) << 3))];
      }
    #pragma unroll
    for (int m = 0; m < 4; m++)
      #pragma unroll
      for (int ks = 0; ks < 2; ks++){
        int ar = wr*64 + m*16 + lo;
        aq[m][ks] = *(const bf16x8*)&As[ar*BK + ((ks*32 + hi*8) ^ ((ar & 7) << 3))];
      }
    #pragma unroll
    for (int m = 0; m < 4; m++)
      #pragma unroll
      for (int n = 0; n < 4; n++)
        #pragma unroll
        for (int ks = 0; ks < 2; ks++)
          acc[m][n] = __builtin_amdgcn_mfma_f32_16x16x32_bf16(aq[m][ks], bq[n][ks], acc[m][n], 0, 0, 0);
    __syncthreads();
  }

  const float* b2e = b2 + (long long)e * O_DIM;
  #pragma unroll
  for (int m = 0; m < 4; m++)
    #pragma unroll
    for (int j = 0; j < 4; j++){
      int rl = wr*64 + m*16 + hi*4 + j;
      if (rl < valid){
        int p = row_pair[seg + m0 + rl];
        float* yr = y + (long long)p * O_DIM;
        #pragma unroll
        for (int n = 0; n < 4; n++){
          int col = n0 + wc*64 + n*16 + lo;
          yr[col] = acc[m][n][j] + b2e[col];
        }
      }
    }
}

// ---------------------------------------------------------------- combine
__global__ __launch_bounds__(256) void combine_kernel(const float* __restrict__ y,
                                                      const int* __restrict__ pe,
                                                      const float* __restrict__ pw,
                                                      float* __restrict__ out){
  int t = blockIdx.x, tid = threadIdx.x;      // 256 threads * float4 = 1024 = O_DIM
  float w0 = pw[2*t], w1 = pw[2*t+1];
  float4 a = ((const float4*)(y + (long long)(2*t) * O_DIM))[tid];
  float4 b = ((const float4*)(y + (long long)(2*t+1) * O_DIM))[tid];
  float4 r;
  r.x = w0 * a.x + w1 * b.x;
  r.y = w0 * a.y + w1 * b.y;
  r.z = w0 * a.z + w1 * b.z;
  r.w = w0 * a.w + w1 * b.w;
  ((float4*)(out + (long long)t * O_DIM))[tid] = r;
}

// ---------------------------------------------------------------- host
extern "C" void kernel_launch(void* const* d_in, const int* in_sizes, int n_in,
                              void* d_out, int out_size, void* d_ws, size_t ws_size,
                              hipStream_t stream){
  const float* x  = (const float*)d_in[0];
  const float* Wg = (const float*)d_in[1];
  const float* bg = (const float*)d_in[2];
  const float* W1 = (const float*)d_in[3];
  const float* b1 = (const float*)d_in[4];
  const float* W2 = (const float*)d_in[5];
  const float* b2 = (const float*)d_in[6];
  float* out = (float*)d_out;

  char* ws = (char*)d_ws;
  size_t off = 0;
  auto alloc = [&](size_t bytes){ size_t r = off; off += (bytes + 255) & ~(size_t)255; return r; };

  unsigned short* W1t    = (unsigned short*)(ws + alloc((size_t)E_NUM * H_DIM * D_DIM * 2));
  unsigned short* W2t    = (unsigned short*)(ws + alloc((size_t)E_NUM * O_DIM * H_DIM * 2));
  unsigned short* xb     = (unsigned short*)(ws + alloc((size_t)NT_TOK * D_DIM * 2));
  unsigned short* hidden = (unsigned short*)(ws + alloc((size_t)PAIRS * H_DIM * 2));
  int*            pe     = (int*)           (ws + alloc(PAIRS * 4));
  float*          pw     = (float*)         (ws + alloc(PAIRS * 4));
  int*            row_pair = (int*)         (ws + alloc(PAIRS * 4));
  int*            cnt    = (int*)           (ws + alloc(64));
  int*            offs   = (int*)           (ws + alloc(64));
  int*            chist  = (int*)           (ws + alloc(32 * E_NUM * 4));
  int*            wi     = (int*)           (ws + alloc(WI_SLOTS * 4));

  // y (33.5 MB) aliases W1t (64 MB): W1t dead after gemm1, y written by gemm2 (stream order)
  float* yp = (float*)W1t;

  if (off > ws_size)
    fprintf(stderr, "kernel_launch: workspace too small: need %zu, have %zu\n", off, ws_size);

  hipMemsetAsync(chist, 0, 32 * E_NUM * 4, stream);          // hist accumulates via atomics
  gate_w1t_kernel<<<NT_TOK/4 + TW1_BLOCKS, 256, 0, stream>>>(x, Wg, bg, W1, xb, W1t, pe, pw, chist);
  scatter_kernel<<<1, 256, 0, stream>>>(pe, chist, cnt, offs, row_pair, wi);
  gemm1_w2t_kernel<<<G1_BLOCKS + TW2_BLOCKS, 256, 0, stream>>>(xb, W1t, W2, W2t, b1,
                                                               row_pair, cnt, offs, wi, hidden);
  gemm2_kernel<<<dim3(O_DIM/128, WI_SLOTS), 256, 0, stream>>>(hidden, W2t, b2, row_pair, cnt, offs, wi, yp);
  combine_kernel<<<NT_TOK, 256, 0, stream>>>(yp, pe, pw, out);
}